// Round 12
// baseline (69.849 us; speedup 1.0000x reference)
//
#include <hip/hip_runtime.h>
#include <hip/hip_bf16.h>
#include <hip/hip_fp16.h>
#include <math.h>

#define B 256
#define S 128
#define E 768
#define E4 192      // E/4 (float4 per row)
#define NA 30
#define NNEG 10

#define K2_KC 96    // k-chunk staged in LDS
#define K2_KR 192   // k-range per block (2 chunks), ksplit = 4

__device__ __forceinline__ float dot4(float4 a, float4 b) {
    return a.x * b.x + a.y * b.y + a.z * b.z + a.w * b.w;
}
__device__ __forceinline__ float wave_reduce_sum(float v) {
#pragma unroll
    for (int off = 32; off; off >>= 1) v += __shfl_down(v, off);
    return v;   // valid on lane 0
}
__device__ __forceinline__ float wave_reduce_max(float v) {
#pragma unroll
    for (int off = 32; off; off >>= 1) v = fmaxf(v, __shfl_down(v, off));
    return v;   // valid on lane 0
}
// convert 4 packed halfs (uint2) -> float4
__device__ __forceinline__ float4 h4_to_f4(uint2 p) {
    __half2* ph = (__half2*)&p;
    float2 f0 = __half22float2(ph[0]);
    float2 f1 = __half22float2(ph[1]);
    return make_float4(f0.x, f0.y, f1.x, f1.y);
}

// ---------------- K1: q-partials (2 per b) + fp16 x-copy + 30 prep blocks ----------------
template <int USE16>
__global__ __launch_bounds__(768) void mean_prep_kernel(const float* __restrict__ x,
                                                        const float* __restrict__ W_red,
                                                        const float* __restrict__ aspect_W,
                                                        float* __restrict__ q,      // [2][B][E]
                                                        float* __restrict__ WredT,
                                                        float* __restrict__ invn,
                                                        __half* __restrict__ xh) {
    int bid = blockIdx.x;
    int tid = threadIdx.x;
    __shared__ __align__(16) float4 part[4][E4];
    __shared__ float red[12];

    if (bid < 2 * B) {
        int b = bid >> 1, half = bid & 1;
        int c = tid % E4;     // float4 column
        int g = tid / E4;     // 0..3 (s-subgroup)
        const float4* xb = (const float4*)(x + (size_t)b * S * E);
        uint2* xhb = (uint2*)(xh + (size_t)b * S * E);
        int s0 = half * 64 + g * 16;
        float4 acc = make_float4(0.f, 0.f, 0.f, 0.f);
#pragma unroll 4
        for (int s = s0; s < s0 + 16; ++s) {
            float4 v = xb[(size_t)s * E4 + c];
            acc.x += v.x; acc.y += v.y; acc.z += v.z; acc.w += v.w;
            if (USE16) {
                __half2 h01 = __floats2half2_rn(v.x, v.y);
                __half2 h23 = __floats2half2_rn(v.z, v.w);
                uint2 pk;
                pk.x = *(unsigned int*)&h01;
                pk.y = *(unsigned int*)&h23;
                xhb[(size_t)s * E4 + c] = pk;
            }
        }
        part[g][c] = acc;
        __syncthreads();
        if (tid < E4) {
            float4 a0 = part[0][c], a1 = part[1][c], a2 = part[2][c], a3 = part[3][c];
            const float inv = 1.0f / (float)S;      // halves sum to the mean
            float4 r;
            r.x = (a0.x + a1.x + a2.x + a3.x) * inv;
            r.y = (a0.y + a1.y + a2.y + a3.y) * inv;
            r.z = (a0.z + a1.z + a2.z + a3.z) * inv;
            r.w = (a0.w + a1.w + a2.w + a3.w) * inv;
            ((float4*)q)[((size_t)half * B + b) * E4 + c] = r;
        }
    } else {
        int a = bid - 2 * B;                       // 0..29
        WredT[(size_t)a * E + tid] = W_red[(size_t)tid * NA + a];
        int wave = tid >> 6, lane = tid & 63;
        float v = aspect_W[(size_t)a * E + tid];
        float ss = wave_reduce_sum(v * v);
        if (lane == 0) red[wave] = ss;
        __syncthreads();
        if (tid == 0) {
            float n = 0.f;
#pragma unroll
            for (int w = 0; w < 12; ++w) n += red[w];
            invn[a] = 1.0f / fmaxf(sqrtf(n), 1e-12f);
        }
    }
}

// ---------------- K2: qW partials (k-split GEMM; sums the 2 q-halves in-stage) ----------------
__global__ __launch_bounds__(256) void qw_partial_kernel(const float* __restrict__ q,   // [2][B][E]
                                                         const float* __restrict__ W_att,
                                                         float* __restrict__ part) {
    int b0 = blockIdx.x * 64;
    int e0 = blockIdx.y * 64;
    int kz = blockIdx.z;
    int k0 = kz * K2_KR;
    int tid = threadIdx.x;

    __shared__ __align__(16) float qs[64][K2_KC + 4];
    __shared__ __align__(16) float ws[K2_KC][64];

    int r0 = (tid >> 3) * 2;
    int c0 = (tid & 7) * 8;

    float4 a00 = make_float4(0,0,0,0), a01 = make_float4(0,0,0,0);
    float4 a10 = make_float4(0,0,0,0), a11 = make_float4(0,0,0,0);

    for (int ch = 0; ch < 2; ++ch) {
        int kc0 = k0 + ch * K2_KC;
        {
            int row = tid >> 2, ks = (tid & 3) * 24;
            const float* src0 = q + (size_t)(b0 + row) * E + kc0 + ks;
            const float* src1 = src0 + (size_t)B * E;
#pragma unroll
            for (int j = 0; j < 6; ++j) {
                float4 v0 = *(const float4*)(src0 + 4 * j);
                float4 v1 = *(const float4*)(src1 + 4 * j);
                v0.x += v1.x; v0.y += v1.y; v0.z += v1.z; v0.w += v1.w;
                *(float4*)&qs[row][ks + 4 * j] = v0;
            }
        }
        for (int i = tid; i < K2_KC * 16; i += 256) {
            int row = i >> 4, e4 = (i & 15) * 4;
            *(float4*)&ws[row][e4] =
                *(const float4*)(W_att + (size_t)(kc0 + row) * E + e0 + e4);
        }
        __syncthreads();
#pragma unroll 4
        for (int k = 0; k < K2_KC; ++k) {
            float qa = qs[r0][k], qb = qs[r0 + 1][k];
            float4 w0 = *(const float4*)&ws[k][c0];
            float4 w1 = *(const float4*)&ws[k][c0 + 4];
            a00.x += qa * w0.x; a00.y += qa * w0.y; a00.z += qa * w0.z; a00.w += qa * w0.w;
            a01.x += qa * w1.x; a01.y += qa * w1.y; a01.z += qa * w1.z; a01.w += qa * w1.w;
            a10.x += qb * w0.x; a10.y += qb * w0.y; a10.z += qb * w0.z; a10.w += qb * w0.w;
            a11.x += qb * w1.x; a11.y += qb * w1.y; a11.z += qb * w1.z; a11.w += qb * w1.w;
        }
        __syncthreads();
    }
    float* dst = part + ((size_t)kz * B + b0 + r0) * E + e0 + c0;
    *(float4*)dst = a00; *(float4*)(dst + 4) = a01;
    *(float4*)(dst + E) = a10; *(float4*)(dst + E + 4) = a11;
}

// ---------------- K3: fused scores + softmax + z (fp16, widened loads) + 30 ortho blocks ----------------
template <int USE16>
__global__ __launch_bounds__(768) void attn_ortho_kernel(const float* __restrict__ x,
                                                         const __half* __restrict__ xh,
                                                         const float* __restrict__ part,
                                                         const float* __restrict__ b_att,
                                                         const float* __restrict__ aspect_W,
                                                         const float* __restrict__ invn,
                                                         float* __restrict__ z_s,
                                                         float* __restrict__ Gpart) {
    int bid = blockIdx.x;
    int tid = threadIdx.x, wave = tid >> 6, lane = tid & 63;
    __shared__ __align__(16) float4 qw4[E4];      // attn: qW[b]; ortho: normalized row i
    __shared__ float att[S];
    __shared__ float red[12];
    __shared__ __align__(16) float4 zpart[8][192]; // sweep-2 partials (2 cols per thread)

    if (bid >= B) {
        int i = bid - B;
        float inv_i = invn[i];
        if (tid < E4) {
            float4 v = ((const float4*)aspect_W)[(size_t)i * E4 + tid];
            v.x *= inv_i; v.y *= inv_i; v.z *= inv_i; v.w *= inv_i;
            qw4[tid] = v;
        }
        __syncthreads();
        float acc = 0.f;
        for (int j = wave; j < NA; j += 12) {
            const float4* aj = (const float4*)(aspect_W + (size_t)j * E);
            float d = 0.f;
#pragma unroll
            for (int jj = 0; jj < 3; ++jj)
                d += dot4(aj[lane + 64 * jj], qw4[lane + 64 * jj]);
            d = wave_reduce_sum(d);
            if (lane == 0) {
                float g = d * invn[j] - ((i == j) ? 1.f : 0.f);
                acc += g * g;
            }
        }
        if (lane == 0) red[wave] = acc;
        __syncthreads();
        if (tid == 0) {
            float s = 0.f;
#pragma unroll
            for (int w = 0; w < 12; ++w) s += red[w];
            Gpart[i] = s;
        }
        return;
    }

    int b = bid;
    const int N4 = B * E / 4;
    if (tid < E4) {
        const float4* p = (const float4*)part;
        size_t base = (size_t)b * E4 + tid;
        float4 s0 = p[base], s1 = p[base + N4], s2 = p[base + 2 * N4], s3 = p[base + 3 * N4];
        float4 bb = ((const float4*)b_att)[tid];
        float4 r;
        r.x = s0.x + s1.x + s2.x + s3.x + bb.x;
        r.y = s0.y + s1.y + s2.y + s3.y + bb.y;
        r.z = s0.z + s1.z + s2.z + s3.z + bb.z;
        r.w = s0.w + s1.w + s2.w + s3.w + bb.w;
        qw4[tid] = r;
    }
    __syncthreads();

    const float4* xb  = (const float4*)(x + (size_t)b * S * E);
    const uint2*  xhb = (const uint2*)(xh + (size_t)b * S * E);

    // sweep 1: scores, 4 rows per wave-iteration (deep MLP over L3 latency)
    for (int p4 = wave; p4 < S / 4; p4 += 12) {
        int sA = 4 * p4;
        float dA = 0.f, dB = 0.f, dC = 0.f, dD = 0.f;
        if (USE16) {
            const uint2* rA = xhb + (size_t)sA * E4;
            const uint2* rB = rA + E4;
            const uint2* rC = rB + E4;
            const uint2* rD = rC + E4;
#pragma unroll
            for (int j = 0; j < 3; ++j) {
                float4 qv = qw4[lane + 64 * j];
                dA += dot4(h4_to_f4(rA[lane + 64 * j]), qv);
                dB += dot4(h4_to_f4(rB[lane + 64 * j]), qv);
                dC += dot4(h4_to_f4(rC[lane + 64 * j]), qv);
                dD += dot4(h4_to_f4(rD[lane + 64 * j]), qv);
            }
        } else {
            const float4* rA = xb + (size_t)sA * E4;
            const float4* rB = rA + E4;
            const float4* rC = rB + E4;
            const float4* rD = rC + E4;
#pragma unroll
            for (int j = 0; j < 3; ++j) {
                float4 qv = qw4[lane + 64 * j];
                dA += dot4(rA[lane + 64 * j], qv);
                dB += dot4(rB[lane + 64 * j], qv);
                dC += dot4(rC[lane + 64 * j], qv);
                dD += dot4(rD[lane + 64 * j], qv);
            }
        }
#pragma unroll
        for (int off = 32; off; off >>= 1) {
            dA += __shfl_down(dA, off);
            dB += __shfl_down(dB, off);
            dC += __shfl_down(dC, off);
            dD += __shfl_down(dD, off);
        }
        if (lane == 0) {
            att[sA] = dA; att[sA + 1] = dB; att[sA + 2] = dC; att[sA + 3] = dD;
        }
    }
    __syncthreads();

    // softmax over 128 (waves 0,1)
    float v = (tid < S) ? att[tid] : -3.4e38f;
    if (tid < S) {
        float m = wave_reduce_max(v);
        if (lane == 0) red[wave] = m;
    }
    __syncthreads();
    float gm = fmaxf(red[0], red[1]);
    float ex = 0.f;
    if (tid < S) {
        ex = expf(v - gm);
        float ss = wave_reduce_sum(ex);
        if (lane == 0) red[4 + wave] = ss;
    }
    __syncthreads();
    float tot = red[4] + red[5];
    if (tid < S) att[tid] = ex / tot;
    __syncthreads();

    // sweep 2: z[b] = att . x[b]
    if (USE16) {
        // 2 fp16-float4 cols per thread via one uint4 (16B) load; 8 s-groups of 16
        int c = tid % 96, g = tid / 96;
        const uint4* xhb4 = (const uint4*)xhb;      // 96 uint4 per row
        float4 acc0 = make_float4(0.f, 0.f, 0.f, 0.f);
        float4 acc1 = make_float4(0.f, 0.f, 0.f, 0.f);
#pragma unroll 4
        for (int s = g * 16; s < g * 16 + 16; ++s) {
            float w = att[s];
            uint4 pk = xhb4[(size_t)s * 96 + c];
            float4 x0 = h4_to_f4(make_uint2(pk.x, pk.y));
            float4 x1 = h4_to_f4(make_uint2(pk.z, pk.w));
            acc0.x += w * x0.x; acc0.y += w * x0.y; acc0.z += w * x0.z; acc0.w += w * x0.w;
            acc1.x += w * x1.x; acc1.y += w * x1.y; acc1.z += w * x1.z; acc1.w += w * x1.w;
        }
        zpart[g][2 * c] = acc0;
        zpart[g][2 * c + 1] = acc1;
        __syncthreads();
        if (tid < E4) {
            float4 r = make_float4(0.f, 0.f, 0.f, 0.f);
#pragma unroll
            for (int gg = 0; gg < 8; ++gg) {
                float4 a = zpart[gg][tid];
                r.x += a.x; r.y += a.y; r.z += a.z; r.w += a.w;
            }
            ((float4*)z_s)[(size_t)b * E4 + tid] = r;
        }
    } else {
        int c = tid % E4, g = tid / E4;
        float4 acc = make_float4(0.f, 0.f, 0.f, 0.f);
#pragma unroll 4
        for (int s = g * 32 + 31; s >= g * 32; --s) {
            float w = att[s];
            float4 xv = xb[(size_t)s * E4 + c];
            acc.x += w * xv.x; acc.y += w * xv.y; acc.z += w * xv.z; acc.w += w * xv.w;
        }
        zpart[g][c] = acc;
        __syncthreads();
        if (tid < E4) {
            float4 r = make_float4(0.f, 0.f, 0.f, 0.f);
#pragma unroll
            for (int gg = 0; gg < 4; ++gg) {
                float4 a = zpart[gg][tid];
                r.x += a.x; r.y += a.y; r.z += a.z; r.w += a.w;
            }
            ((float4*)z_s)[(size_t)b * E4 + tid] = r;
        }
    }
}

// ---------------- K4: composition + reconstruction + margin (768 thr) ----------------
__global__ __launch_bounds__(768) void recon_margin_kernel(const float* __restrict__ z_s,
                                                           const float* __restrict__ WredT,
                                                           const float* __restrict__ b_red,
                                                           const float* __restrict__ aspect_W,
                                                           const int* __restrict__ neg_idx,
                                                           float* __restrict__ recon,
                                                           float* __restrict__ mpart) {
    int b = blockIdx.x;
    int tid = threadIdx.x, wave = tid >> 6, lane = tid & 63;
    __shared__ __align__(16) float4 z4[E4];
    __shared__ float comp[NA];
    __shared__ __align__(16) float r_sh[E];
    __shared__ float red[12];
    __shared__ float dots[12];

    if (tid < E4) z4[tid] = ((const float4*)(z_s + (size_t)b * E))[tid];
    __syncthreads();

    for (int a = wave; a < NA; a += 12) {
        const float4* wr = (const float4*)(WredT + (size_t)a * E);
        float d = 0.f;
#pragma unroll
        for (int j = 0; j < 3; ++j)
            d += dot4(wr[lane + 64 * j], z4[lane + 64 * j]);
        d = wave_reduce_sum(d);
        if (lane == 0) comp[a] = d + b_red[a];
    }
    __syncthreads();

    if (wave == 0) {
        float v = (lane < NA) ? comp[lane] : -3.4e38f;
        float m = wave_reduce_max(v);
        m = __shfl(m, 0);
        float e = (lane < NA) ? expf(v - m) : 0.f;
        float ssum = wave_reduce_sum(e);
        ssum = __shfl(ssum, 0);
        if (lane < NA) comp[lane] = e / ssum;
    }
    __syncthreads();

    float r = 0.f;
    for (int a = 0; a < NA; ++a)
        r += comp[a] * aspect_W[(size_t)a * E + tid];
    recon[(size_t)b * E + tid] = r;
    r_sh[tid] = r;
    float sq = wave_reduce_sum(r * r);
    if (lane == 0) red[wave] = sq;
    __syncthreads();
    float tot = 0.f;
#pragma unroll
    for (int w = 0; w < 12; ++w) tot += red[w];
    float inv = 1.0f / fmaxf(sqrtf(tot), 1e-12f);

    if (wave <= NNEG) {
        int row = (wave == 0) ? b : neg_idx[b * NNEG + (wave - 1)];
        const float4* zr = (const float4*)(z_s + (size_t)row * E);
        const float4* rr = (const float4*)r_sh;
        float acc = 0.f;
#pragma unroll
        for (int j = 0; j < 3; ++j)
            acc += dot4(zr[lane + 64 * j], rr[lane + 64 * j]);
        acc = wave_reduce_sum(acc);
        if (lane == 0) dots[wave] = acc;
    }
    __syncthreads();
    if (tid == 0) {
        float pos = dots[0] * inv;
        float ssum = 0.f;
        for (int n = 1; n <= NNEG; ++n)
            ssum += fmaxf(1.f - pos + dots[n] * inv, 0.f);
        mpart[b] = ssum;
    }
}

// ---------------- K5: final scalar loss ----------------
__global__ __launch_bounds__(256) void loss_kernel(const float* __restrict__ Gpart,
                                                   const float* __restrict__ mpart,
                                                   float* __restrict__ loss_out) {
    int tid = threadIdx.x, wave = tid >> 6, lane = tid & 63;
    __shared__ float ra[4], rb[4];
    float fr = (tid < NA) ? Gpart[tid] : 0.f;
    fr = wave_reduce_sum(fr);
    if (lane == 0) ra[wave] = fr;
    float mp = mpart[tid];
    mp = wave_reduce_sum(mp);
    if (lane == 0) rb[wave] = mp;
    __syncthreads();
    if (tid == 0) {
        float frob = sqrtf(ra[0] + ra[1] + ra[2] + ra[3]);
        float msum = rb[0] + rb[1] + rb[2] + rb[3];
        loss_out[0] = frob + msum * (1.0f / (float)(B * NNEG));
    }
}

extern "C" void kernel_launch(void* const* d_in, const int* in_sizes, int n_in,
                              void* d_out, int out_size, void* d_ws, size_t ws_size,
                              hipStream_t stream) {
    const float* x        = (const float*)d_in[0];
    const float* W_att    = (const float*)d_in[1];
    const float* b_att    = (const float*)d_in[2];
    const float* W_red    = (const float*)d_in[3];
    const float* b_red    = (const float*)d_in[4];
    const float* aspect_W = (const float*)d_in[5];
    const int*   neg_idx  = (const int*)d_in[6];

    float* out   = (float*)d_out;
    float* z_s   = out;                       // [B,E]
    float* recon = out + (size_t)B * E;       // [B,E]
    float* loss  = out + (size_t)2 * B * E;   // [1]

    float* ws    = (float*)d_ws;
    float* q     = ws;                        // 2*B*E
    float* part2 = q + (size_t)2 * B * E;     // 4*B*E
    float* WredT = part2 + (size_t)4 * B * E; // NA*E
    float* invn  = WredT + (size_t)NA * E;    // 32
    float* Gpart = invn + 32;                 // 32
    float* mpart = Gpart + 32;                // B
    float* endf  = mpart + B;

    size_t base_floats = (size_t)(endf - ws);
    size_t need = base_floats * sizeof(float) + (size_t)B * S * E * sizeof(__half);
    bool use16 = (ws_size >= need);
    __half* xh = (__half*)(ws + base_floats);

    if (use16) {
        mean_prep_kernel<1><<<2 * B + NA, 768, 0, stream>>>(x, W_red, aspect_W, q, WredT, invn, xh);
        qw_partial_kernel<<<dim3(4, 12, 4), 256, 0, stream>>>(q, W_att, part2);
        attn_ortho_kernel<1><<<B + NA, 768, 0, stream>>>(x, xh, part2, b_att, aspect_W, invn, z_s, Gpart);
    } else {
        mean_prep_kernel<0><<<2 * B + NA, 768, 0, stream>>>(x, W_red, aspect_W, q, WredT, invn, xh);
        qw_partial_kernel<<<dim3(4, 12, 4), 256, 0, stream>>>(q, W_att, part2);
        attn_ortho_kernel<0><<<B + NA, 768, 0, stream>>>(x, xh, part2, b_att, aspect_W, invn, z_s, Gpart);
    }
    recon_margin_kernel<<<B, 768, 0, stream>>>(z_s, WredT, b_red, aspect_W, neg_idx, recon, mpart);
    loss_kernel<<<1, 256, 0, stream>>>(Gpart, mpart, loss);
}

// Round 13
// 67.759 us; speedup vs baseline: 1.0308x; 1.0308x over previous
//
#include <hip/hip_runtime.h>
#include <hip/hip_bf16.h>
#include <hip/hip_fp16.h>
#include <math.h>

#define B 256
#define S 128
#define E 768
#define E4 192      // E/4 (float4 per row)
#define NA 30
#define NNEG 10

#define K2_KC 96    // k-chunk staged in LDS
#define K2_KR 192   // k-range per block (2 chunks), ksplit = 4

__device__ __forceinline__ float dot4(float4 a, float4 b) {
    return a.x * b.x + a.y * b.y + a.z * b.z + a.w * b.w;
}
__device__ __forceinline__ float wave_reduce_sum(float v) {
#pragma unroll
    for (int off = 32; off; off >>= 1) v += __shfl_down(v, off);
    return v;   // valid on lane 0
}
__device__ __forceinline__ float wave_reduce_max(float v) {
#pragma unroll
    for (int off = 32; off; off >>= 1) v = fmaxf(v, __shfl_down(v, off));
    return v;   // valid on lane 0
}
__device__ __forceinline__ float4 h4_to_f4(uint2 p) {
    __half2* ph = (__half2*)&p;
    float2 f0 = __half22float2(ph[0]);
    float2 f1 = __half22float2(ph[1]);
    return make_float4(f0.x, f0.y, f1.x, f1.y);
}

// ---------------- K1: q-partials (2 per b) + fp16 x-copy + 30 prep blocks ----------------
template <int USE16>
__global__ __launch_bounds__(768) void mean_prep_kernel(const float* __restrict__ x,
                                                        const float* __restrict__ W_red,
                                                        const float* __restrict__ aspect_W,
                                                        float* __restrict__ q,      // [2][B][E]
                                                        float* __restrict__ WredT,
                                                        float* __restrict__ invn,
                                                        __half* __restrict__ xh) {
    int bid = blockIdx.x;
    int tid = threadIdx.x;
    __shared__ __align__(16) float4 part[4][E4];
    __shared__ float red[12];

    if (bid < 2 * B) {
        int b = bid >> 1, half = bid & 1;
        int c = tid % E4;     // float4 column
        int g = tid / E4;     // 0..3 (s-subgroup)
        const float4* xb = (const float4*)(x + (size_t)b * S * E);
        uint2* xhb = (uint2*)(xh + (size_t)b * S * E);
        int s0 = half * 64 + g * 16;
        float4 acc = make_float4(0.f, 0.f, 0.f, 0.f);
#pragma unroll 4
        for (int s = s0; s < s0 + 16; ++s) {
            float4 v = xb[(size_t)s * E4 + c];
            acc.x += v.x; acc.y += v.y; acc.z += v.z; acc.w += v.w;
            if (USE16) {
                __half2 h01 = __floats2half2_rn(v.x, v.y);
                __half2 h23 = __floats2half2_rn(v.z, v.w);
                uint2 pk;
                pk.x = *(unsigned int*)&h01;
                pk.y = *(unsigned int*)&h23;
                xhb[(size_t)s * E4 + c] = pk;
            }
        }
        part[g][c] = acc;
        __syncthreads();
        if (tid < E4) {
            float4 a0 = part[0][c], a1 = part[1][c], a2 = part[2][c], a3 = part[3][c];
            const float inv = 1.0f / (float)S;      // halves sum to the mean
            float4 r;
            r.x = (a0.x + a1.x + a2.x + a3.x) * inv;
            r.y = (a0.y + a1.y + a2.y + a3.y) * inv;
            r.z = (a0.z + a1.z + a2.z + a3.z) * inv;
            r.w = (a0.w + a1.w + a2.w + a3.w) * inv;
            ((float4*)q)[((size_t)half * B + b) * E4 + c] = r;
        }
    } else {
        int a = bid - 2 * B;                       // 0..29
        WredT[(size_t)a * E + tid] = W_red[(size_t)tid * NA + a];
        int wave = tid >> 6, lane = tid & 63;
        float v = aspect_W[(size_t)a * E + tid];
        float ss = wave_reduce_sum(v * v);
        if (lane == 0) red[wave] = ss;
        __syncthreads();
        if (tid == 0) {
            float n = 0.f;
#pragma unroll
            for (int w = 0; w < 12; ++w) n += red[w];
            invn[a] = 1.0f / fmaxf(sqrtf(n), 1e-12f);
        }
    }
}

// ---------------- K2: qW partials (k-split GEMM; sums the 2 q-halves in-stage) ----------------
__global__ __launch_bounds__(256) void qw_partial_kernel(const float* __restrict__ q,   // [2][B][E]
                                                         const float* __restrict__ W_att,
                                                         float* __restrict__ part) {
    int b0 = blockIdx.x * 64;
    int e0 = blockIdx.y * 64;
    int kz = blockIdx.z;
    int k0 = kz * K2_KR;
    int tid = threadIdx.x;

    __shared__ __align__(16) float qs[64][K2_KC + 4];
    __shared__ __align__(16) float ws[K2_KC][64];

    int r0 = (tid >> 3) * 2;
    int c0 = (tid & 7) * 8;

    float4 a00 = make_float4(0,0,0,0), a01 = make_float4(0,0,0,0);
    float4 a10 = make_float4(0,0,0,0), a11 = make_float4(0,0,0,0);

    for (int ch = 0; ch < 2; ++ch) {
        int kc0 = k0 + ch * K2_KC;
        {
            int row = tid >> 2, ks = (tid & 3) * 24;
            const float* src0 = q + (size_t)(b0 + row) * E + kc0 + ks;
            const float* src1 = src0 + (size_t)B * E;
#pragma unroll
            for (int j = 0; j < 6; ++j) {
                float4 v0 = *(const float4*)(src0 + 4 * j);
                float4 v1 = *(const float4*)(src1 + 4 * j);
                v0.x += v1.x; v0.y += v1.y; v0.z += v1.z; v0.w += v1.w;
                *(float4*)&qs[row][ks + 4 * j] = v0;
            }
        }
        for (int i = tid; i < K2_KC * 16; i += 256) {
            int row = i >> 4, e4 = (i & 15) * 4;
            *(float4*)&ws[row][e4] =
                *(const float4*)(W_att + (size_t)(kc0 + row) * E + e0 + e4);
        }
        __syncthreads();
#pragma unroll 4
        for (int k = 0; k < K2_KC; ++k) {
            float qa = qs[r0][k], qb = qs[r0 + 1][k];
            float4 w0 = *(const float4*)&ws[k][c0];
            float4 w1 = *(const float4*)&ws[k][c0 + 4];
            a00.x += qa * w0.x; a00.y += qa * w0.y; a00.z += qa * w0.z; a00.w += qa * w0.w;
            a01.x += qa * w1.x; a01.y += qa * w1.y; a01.z += qa * w1.z; a01.w += qa * w1.w;
            a10.x += qb * w0.x; a10.y += qb * w0.y; a10.z += qb * w0.z; a10.w += qb * w0.w;
            a11.x += qb * w1.x; a11.y += qb * w1.y; a11.z += qb * w1.z; a11.w += qb * w1.w;
        }
        __syncthreads();
    }
    float* dst = part + ((size_t)kz * B + b0 + r0) * E + e0 + c0;
    *(float4*)dst = a00; *(float4*)(dst + 4) = a01;
    *(float4*)(dst + E) = a10; *(float4*)(dst + E + 4) = a11;
}

// ---------------- K3: single-sweep register-resident online-softmax attention ----------------
// 8 waves/block; wave w owns rows [16w,16w+16). Lane holds 3 float4 columns of each
// row in registers: score via butterfly shuffle, online m/l/z update, z acc from regs.
// x (fp16) read ONCE. Final 8-way rescaled combine in LDS. +30 ortho blocks.
template <int USE16>
__global__ __launch_bounds__(512) void attn_ortho_kernel(const float* __restrict__ x,
                                                         const __half* __restrict__ xh,
                                                         const float* __restrict__ part,
                                                         const float* __restrict__ b_att,
                                                         const float* __restrict__ aspect_W,
                                                         const float* __restrict__ invn,
                                                         float* __restrict__ z_s,
                                                         float* __restrict__ Gpart) {
    int bid = blockIdx.x;
    int tid = threadIdx.x, wave = tid >> 6, lane = tid & 63;
    __shared__ __align__(16) float4 qw4[E4];       // attn: qW[b]; ortho: normalized row i
    __shared__ __align__(16) float4 zw[8][E4];     // per-wave z partials (24 KB)
    __shared__ float wm[8], wl[8];
    __shared__ float red[8];

    if (bid >= B) {
        // ---- ortho block (8 waves): row i of G = Tn Tn^T - I ----
        int i = bid - B;
        float inv_i = invn[i];
        if (tid < E4) {
            float4 v = ((const float4*)aspect_W)[(size_t)i * E4 + tid];
            v.x *= inv_i; v.y *= inv_i; v.z *= inv_i; v.w *= inv_i;
            qw4[tid] = v;
        }
        __syncthreads();
        float acc = 0.f;
        for (int j = wave; j < NA; j += 8) {
            const float4* aj = (const float4*)(aspect_W + (size_t)j * E);
            float d = 0.f;
#pragma unroll
            for (int jj = 0; jj < 3; ++jj)
                d += dot4(aj[lane + 64 * jj], qw4[lane + 64 * jj]);
            d = wave_reduce_sum(d);
            if (lane == 0) {
                float g = d * invn[j] - ((i == j) ? 1.f : 0.f);
                acc += g * g;
            }
        }
        if (lane == 0) red[wave] = acc;
        __syncthreads();
        if (tid == 0) {
            float s = 0.f;
#pragma unroll
            for (int w = 0; w < 8; ++w) s += red[w];
            Gpart[i] = s;
        }
        return;
    }

    int b = bid;
    const int N4 = B * E / 4;
    // stage qW[b] = sum of 4 k-partials + b_att
    if (tid < E4) {
        const float4* p = (const float4*)part;
        size_t base = (size_t)b * E4 + tid;
        float4 s0 = p[base], s1 = p[base + N4], s2 = p[base + 2 * N4], s3 = p[base + 3 * N4];
        float4 bb = ((const float4*)b_att)[tid];
        float4 r;
        r.x = s0.x + s1.x + s2.x + s3.x + bb.x;
        r.y = s0.y + s1.y + s2.y + s3.y + bb.y;
        r.z = s0.z + s1.z + s2.z + s3.z + bb.z;
        r.w = s0.w + s1.w + s2.w + s3.w + bb.w;
        qw4[tid] = r;
    }
    __syncthreads();

    // per-lane qW fragment in registers
    float4 q0 = qw4[lane], q1 = qw4[lane + 64], q2 = qw4[lane + 128];

    float m = -3.4e38f, l = 0.f;
    float4 a0 = make_float4(0.f, 0.f, 0.f, 0.f);
    float4 a1 = a0, a2 = a0;

    const uint2*  xhb = (const uint2*)(xh + (size_t)b * S * E);
    const float4* xb  = (const float4*)(x + (size_t)b * S * E);
    int s0 = wave * 16;

#pragma unroll
    for (int i = 0; i < 16; i += 2) {
        float4 xA0, xA1, xA2, xB0, xB1, xB2;
        if (USE16) {
            const uint2* rA = xhb + (size_t)(s0 + i) * E4;
            const uint2* rB = rA + E4;
            xA0 = h4_to_f4(rA[lane]); xA1 = h4_to_f4(rA[lane + 64]); xA2 = h4_to_f4(rA[lane + 128]);
            xB0 = h4_to_f4(rB[lane]); xB1 = h4_to_f4(rB[lane + 64]); xB2 = h4_to_f4(rB[lane + 128]);
        } else {
            const float4* rA = xb + (size_t)(s0 + i) * E4;
            const float4* rB = rA + E4;
            xA0 = rA[lane]; xA1 = rA[lane + 64]; xA2 = rA[lane + 128];
            xB0 = rB[lane]; xB1 = rB[lane + 64]; xB2 = rB[lane + 128];
        }
        float dA = dot4(xA0, q0) + dot4(xA1, q1) + dot4(xA2, q2);
        float dB = dot4(xB0, q0) + dot4(xB1, q1) + dot4(xB2, q2);
#pragma unroll
        for (int off = 32; off; off >>= 1) {
            dA += __shfl_xor(dA, off);
            dB += __shfl_xor(dB, off);
        }
        // online softmax update (identical in every lane of the wave)
        float tm = fmaxf(m, fmaxf(dA, dB));
        float sc = __expf(m - tm);             // first iter: exp(-inf)=0
        float eA = __expf(dA - tm);
        float eB = __expf(dB - tm);
        l = l * sc + eA + eB;
        a0.x = a0.x * sc + eA * xA0.x + eB * xB0.x;
        a0.y = a0.y * sc + eA * xA0.y + eB * xB0.y;
        a0.z = a0.z * sc + eA * xA0.z + eB * xB0.z;
        a0.w = a0.w * sc + eA * xA0.w + eB * xB0.w;
        a1.x = a1.x * sc + eA * xA1.x + eB * xB1.x;
        a1.y = a1.y * sc + eA * xA1.y + eB * xB1.y;
        a1.z = a1.z * sc + eA * xA1.z + eB * xB1.z;
        a1.w = a1.w * sc + eA * xA1.w + eB * xB1.w;
        a2.x = a2.x * sc + eA * xA2.x + eB * xB2.x;
        a2.y = a2.y * sc + eA * xA2.y + eB * xB2.y;
        a2.z = a2.z * sc + eA * xA2.z + eB * xB2.z;
        a2.w = a2.w * sc + eA * xA2.w + eB * xB2.w;
        m = tm;
    }

    // per-wave partials to LDS
    zw[wave][lane] = a0;
    zw[wave][lane + 64] = a1;
    zw[wave][lane + 128] = a2;
    if (lane == 0) { wm[wave] = m; wl[wave] = l; }
    __syncthreads();

    // combine 8 waves with rescale (threads 0..191)
    if (tid < E4) {
        float M = wm[0];
#pragma unroll
        for (int w = 1; w < 8; ++w) M = fmaxf(M, wm[w]);
        float L = 0.f;
        float4 z = make_float4(0.f, 0.f, 0.f, 0.f);
#pragma unroll
        for (int w = 0; w < 8; ++w) {
            float f = __expf(wm[w] - M);
            float4 a = zw[w][tid];
            z.x += f * a.x; z.y += f * a.y; z.z += f * a.z; z.w += f * a.w;
            L += f * wl[w];
        }
        float invL = 1.0f / L;
        z.x *= invL; z.y *= invL; z.z *= invL; z.w *= invL;
        ((float4*)z_s)[(size_t)b * E4 + tid] = z;
    }
}

// ---------------- K4: composition + reconstruction + margin (768 thr) ----------------
__global__ __launch_bounds__(768) void recon_margin_kernel(const float* __restrict__ z_s,
                                                           const float* __restrict__ WredT,
                                                           const float* __restrict__ b_red,
                                                           const float* __restrict__ aspect_W,
                                                           const int* __restrict__ neg_idx,
                                                           float* __restrict__ recon,
                                                           float* __restrict__ mpart) {
    int b = blockIdx.x;
    int tid = threadIdx.x, wave = tid >> 6, lane = tid & 63;
    __shared__ __align__(16) float4 z4[E4];
    __shared__ float comp[NA];
    __shared__ __align__(16) float r_sh[E];
    __shared__ float red[12];
    __shared__ float dots[12];

    if (tid < E4) z4[tid] = ((const float4*)(z_s + (size_t)b * E))[tid];
    __syncthreads();

    for (int a = wave; a < NA; a += 12) {
        const float4* wr = (const float4*)(WredT + (size_t)a * E);
        float d = 0.f;
#pragma unroll
        for (int j = 0; j < 3; ++j)
            d += dot4(wr[lane + 64 * j], z4[lane + 64 * j]);
        d = wave_reduce_sum(d);
        if (lane == 0) comp[a] = d + b_red[a];
    }
    __syncthreads();

    if (wave == 0) {
        float v = (lane < NA) ? comp[lane] : -3.4e38f;
        float m = wave_reduce_max(v);
        m = __shfl(m, 0);
        float e = (lane < NA) ? expf(v - m) : 0.f;
        float ssum = wave_reduce_sum(e);
        ssum = __shfl(ssum, 0);
        if (lane < NA) comp[lane] = e / ssum;
    }
    __syncthreads();

    float r = 0.f;
    for (int a = 0; a < NA; ++a)
        r += comp[a] * aspect_W[(size_t)a * E + tid];
    recon[(size_t)b * E + tid] = r;
    r_sh[tid] = r;
    float sq = wave_reduce_sum(r * r);
    if (lane == 0) red[wave] = sq;
    __syncthreads();
    float tot = 0.f;
#pragma unroll
    for (int w = 0; w < 12; ++w) tot += red[w];
    float inv = 1.0f / fmaxf(sqrtf(tot), 1e-12f);

    if (wave <= NNEG) {
        int row = (wave == 0) ? b : neg_idx[b * NNEG + (wave - 1)];
        const float4* zr = (const float4*)(z_s + (size_t)row * E);
        const float4* rr = (const float4*)r_sh;
        float acc = 0.f;
#pragma unroll
        for (int j = 0; j < 3; ++j)
            acc += dot4(zr[lane + 64 * j], rr[lane + 64 * j]);
        acc = wave_reduce_sum(acc);
        if (lane == 0) dots[wave] = acc;
    }
    __syncthreads();
    if (tid == 0) {
        float pos = dots[0] * inv;
        float ssum = 0.f;
        for (int n = 1; n <= NNEG; ++n)
            ssum += fmaxf(1.f - pos + dots[n] * inv, 0.f);
        mpart[b] = ssum;
    }
}

// ---------------- K5: final scalar loss ----------------
__global__ __launch_bounds__(256) void loss_kernel(const float* __restrict__ Gpart,
                                                   const float* __restrict__ mpart,
                                                   float* __restrict__ loss_out) {
    int tid = threadIdx.x, wave = tid >> 6, lane = tid & 63;
    __shared__ float ra[4], rb[4];
    float fr = (tid < NA) ? Gpart[tid] : 0.f;
    fr = wave_reduce_sum(fr);
    if (lane == 0) ra[wave] = fr;
    float mp = mpart[tid];
    mp = wave_reduce_sum(mp);
    if (lane == 0) rb[wave] = mp;
    __syncthreads();
    if (tid == 0) {
        float frob = sqrtf(ra[0] + ra[1] + ra[2] + ra[3]);
        float msum = rb[0] + rb[1] + rb[2] + rb[3];
        loss_out[0] = frob + msum * (1.0f / (float)(B * NNEG));
    }
}

extern "C" void kernel_launch(void* const* d_in, const int* in_sizes, int n_in,
                              void* d_out, int out_size, void* d_ws, size_t ws_size,
                              hipStream_t stream) {
    const float* x        = (const float*)d_in[0];
    const float* W_att    = (const float*)d_in[1];
    const float* b_att    = (const float*)d_in[2];
    const float* W_red    = (const float*)d_in[3];
    const float* b_red    = (const float*)d_in[4];
    const float* aspect_W = (const float*)d_in[5];
    const int*   neg_idx  = (const int*)d_in[6];

    float* out   = (float*)d_out;
    float* z_s   = out;                       // [B,E]
    float* recon = out + (size_t)B * E;       // [B,E]
    float* loss  = out + (size_t)2 * B * E;   // [1]

    float* ws    = (float*)d_ws;
    float* q     = ws;                        // 2*B*E
    float* part2 = q + (size_t)2 * B * E;     // 4*B*E
    float* WredT = part2 + (size_t)4 * B * E; // NA*E
    float* invn  = WredT + (size_t)NA * E;    // 32
    float* Gpart = invn + 32;                 // 32
    float* mpart = Gpart + 32;                // B
    float* endf  = mpart + B;

    size_t base_floats = (size_t)(endf - ws);
    size_t need = base_floats * sizeof(float) + (size_t)B * S * E * sizeof(__half);
    bool use16 = (ws_size >= need);
    __half* xh = (__half*)(ws + base_floats);

    if (use16) {
        mean_prep_kernel<1><<<2 * B + NA, 768, 0, stream>>>(x, W_red, aspect_W, q, WredT, invn, xh);
        qw_partial_kernel<<<dim3(4, 12, 4), 256, 0, stream>>>(q, W_att, part2);
        attn_ortho_kernel<1><<<B + NA, 512, 0, stream>>>(x, xh, part2, b_att, aspect_W, invn, z_s, Gpart);
    } else {
        mean_prep_kernel<0><<<2 * B + NA, 768, 0, stream>>>(x, W_red, aspect_W, q, WredT, invn, xh);
        qw_partial_kernel<<<dim3(4, 12, 4), 256, 0, stream>>>(q, W_att, part2);
        attn_ortho_kernel<0><<<B + NA, 512, 0, stream>>>(x, xh, part2, b_att, aspect_W, invn, z_s, Gpart);
    }
    recon_margin_kernel<<<B, 768, 0, stream>>>(z_s, WredT, b_red, aspect_W, neg_idx, recon, mpart);
    loss_kernel<<<1, 256, 0, stream>>>(Gpart, mpart, loss);
}

// Round 14
// 64.197 us; speedup vs baseline: 1.0880x; 1.0555x over previous
//
#include <hip/hip_runtime.h>
#include <hip/hip_bf16.h>
#include <hip/hip_fp16.h>
#include <math.h>

#define B 256
#define S 128
#define E 768
#define E4 192      // E/4 (float4 per row)
#define NA 30
#define NNEG 10

#define K2_KC 96    // k-chunk per block; ksplit = 8

__device__ __forceinline__ float dot4(float4 a, float4 b) {
    return a.x * b.x + a.y * b.y + a.z * b.z + a.w * b.w;
}
__device__ __forceinline__ float wave_reduce_sum(float v) {
#pragma unroll
    for (int off = 32; off; off >>= 1) v += __shfl_down(v, off);
    return v;   // valid on lane 0
}
__device__ __forceinline__ float wave_reduce_max(float v) {
#pragma unroll
    for (int off = 32; off; off >>= 1) v = fmaxf(v, __shfl_down(v, off));
    return v;   // valid on lane 0
}
__device__ __forceinline__ float4 h4_to_f4(uint2 p) {
    __half2* ph = (__half2*)&p;
    float2 f0 = __half22float2(ph[0]);
    float2 f1 = __half22float2(ph[1]);
    return make_float4(f0.x, f0.y, f1.x, f1.y);
}

// ---------------- K1: q-partials (2 per b) + fp16 x-copy + 30 prep blocks ----------------
template <int USE16>
__global__ __launch_bounds__(768) void mean_prep_kernel(const float* __restrict__ x,
                                                        const float* __restrict__ W_red,
                                                        const float* __restrict__ aspect_W,
                                                        float* __restrict__ q,      // [2][B][E]
                                                        float* __restrict__ WredT,
                                                        float* __restrict__ invn,
                                                        __half* __restrict__ xh) {
    int bid = blockIdx.x;
    int tid = threadIdx.x;
    __shared__ __align__(16) float4 part[4][E4];
    __shared__ float red[12];

    if (bid < 2 * B) {
        int b = bid >> 1, half = bid & 1;
        int c = tid % E4;     // float4 column
        int g = tid / E4;     // 0..3 (s-subgroup)
        const float4* xb = (const float4*)(x + (size_t)b * S * E);
        uint2* xhb = (uint2*)(xh + (size_t)b * S * E);
        int s0 = half * 64 + g * 16;
        float4 acc = make_float4(0.f, 0.f, 0.f, 0.f);
#pragma unroll 4
        for (int s = s0; s < s0 + 16; ++s) {
            float4 v = xb[(size_t)s * E4 + c];
            acc.x += v.x; acc.y += v.y; acc.z += v.z; acc.w += v.w;
            if (USE16) {
                __half2 h01 = __floats2half2_rn(v.x, v.y);
                __half2 h23 = __floats2half2_rn(v.z, v.w);
                uint2 pk;
                pk.x = *(unsigned int*)&h01;
                pk.y = *(unsigned int*)&h23;
                xhb[(size_t)s * E4 + c] = pk;
            }
        }
        part[g][c] = acc;
        __syncthreads();
        if (tid < E4) {
            float4 a0 = part[0][c], a1 = part[1][c], a2 = part[2][c], a3 = part[3][c];
            const float inv = 1.0f / (float)S;      // halves sum to the mean
            float4 r;
            r.x = (a0.x + a1.x + a2.x + a3.x) * inv;
            r.y = (a0.y + a1.y + a2.y + a3.y) * inv;
            r.z = (a0.z + a1.z + a2.z + a3.z) * inv;
            r.w = (a0.w + a1.w + a2.w + a3.w) * inv;
            ((float4*)q)[((size_t)half * B + b) * E4 + c] = r;
        }
    } else {
        int a = bid - 2 * B;                       // 0..29
        WredT[(size_t)a * E + tid] = W_red[(size_t)tid * NA + a];
        int wave = tid >> 6, lane = tid & 63;
        float v = aspect_W[(size_t)a * E + tid];
        float ss = wave_reduce_sum(v * v);
        if (lane == 0) red[wave] = ss;
        __syncthreads();
        if (tid == 0) {
            float n = 0.f;
#pragma unroll
            for (int w = 0; w < 12; ++w) n += red[w];
            invn[a] = 1.0f / fmaxf(sqrtf(n), 1e-12f);
        }
    }
}

// ---------------- K2: qW partials (k-split 8 GEMM; sums the 2 q-halves in-stage) ----------------
__global__ __launch_bounds__(256) void qw_partial_kernel(const float* __restrict__ q,   // [2][B][E]
                                                         const float* __restrict__ W_att,
                                                         float* __restrict__ part) {   // [8][B][E]
    int b0 = blockIdx.x * 64;
    int e0 = blockIdx.y * 64;
    int kz = blockIdx.z;
    int k0 = kz * K2_KC;
    int tid = threadIdx.x;

    __shared__ __align__(16) float qs[64][K2_KC + 4];
    __shared__ __align__(16) float ws[K2_KC][64];

    int r0 = (tid >> 3) * 2;
    int c0 = (tid & 7) * 8;

    float4 a00 = make_float4(0,0,0,0), a01 = make_float4(0,0,0,0);
    float4 a10 = make_float4(0,0,0,0), a11 = make_float4(0,0,0,0);

    {
        int row = tid >> 2, ks = (tid & 3) * 24;
        const float* src0 = q + (size_t)(b0 + row) * E + k0 + ks;
        const float* src1 = src0 + (size_t)B * E;
#pragma unroll
        for (int j = 0; j < 6; ++j) {
            float4 v0 = *(const float4*)(src0 + 4 * j);
            float4 v1 = *(const float4*)(src1 + 4 * j);
            v0.x += v1.x; v0.y += v1.y; v0.z += v1.z; v0.w += v1.w;
            *(float4*)&qs[row][ks + 4 * j] = v0;
        }
    }
    for (int i = tid; i < K2_KC * 16; i += 256) {
        int row = i >> 4, e4 = (i & 15) * 4;
        *(float4*)&ws[row][e4] =
            *(const float4*)(W_att + (size_t)(k0 + row) * E + e0 + e4);
    }
    __syncthreads();
#pragma unroll 4
    for (int k = 0; k < K2_KC; ++k) {
        float qa = qs[r0][k], qb = qs[r0 + 1][k];
        float4 w0 = *(const float4*)&ws[k][c0];
        float4 w1 = *(const float4*)&ws[k][c0 + 4];
        a00.x += qa * w0.x; a00.y += qa * w0.y; a00.z += qa * w0.z; a00.w += qa * w0.w;
        a01.x += qa * w1.x; a01.y += qa * w1.y; a01.z += qa * w1.z; a01.w += qa * w1.w;
        a10.x += qb * w0.x; a10.y += qb * w0.y; a10.z += qb * w0.z; a10.w += qb * w0.w;
        a11.x += qb * w1.x; a11.y += qb * w1.y; a11.z += qb * w1.z; a11.w += qb * w1.w;
    }
    float* dst = part + ((size_t)kz * B + b0 + r0) * E + e0 + c0;
    *(float4*)dst = a00; *(float4*)(dst + 4) = a01;
    *(float4*)(dst + E) = a10; *(float4*)(dst + E + 4) = a11;
}

// ---------------- K3: single-sweep online-softmax attention, dual chains + 30 ortho blocks ----------------
template <int USE16>
__global__ __launch_bounds__(512) void attn_ortho_kernel(const float* __restrict__ x,
                                                         const __half* __restrict__ xh,
                                                         const float* __restrict__ part,   // [8][B][E]
                                                         const float* __restrict__ b_att,
                                                         const float* __restrict__ aspect_W,
                                                         const float* __restrict__ invn,
                                                         float* __restrict__ z_s,
                                                         float* __restrict__ Gpart) {
    int bid = blockIdx.x;
    int tid = threadIdx.x, wave = tid >> 6, lane = tid & 63;
    __shared__ __align__(16) float4 qw4[E4];       // attn: qW[b]; ortho: normalized row i
    __shared__ __align__(16) float4 zw[8][E4];     // per-wave z partials (24 KB)
    __shared__ float wm[8], wl[8];
    __shared__ float red[8];

    if (bid >= B) {
        // ---- ortho block (8 waves): row i of G = Tn Tn^T - I ----
        int i = bid - B;
        float inv_i = invn[i];
        if (tid < E4) {
            float4 v = ((const float4*)aspect_W)[(size_t)i * E4 + tid];
            v.x *= inv_i; v.y *= inv_i; v.z *= inv_i; v.w *= inv_i;
            qw4[tid] = v;
        }
        __syncthreads();
        float acc = 0.f;
        for (int j = wave; j < NA; j += 8) {
            const float4* aj = (const float4*)(aspect_W + (size_t)j * E);
            float d = 0.f;
#pragma unroll
            for (int jj = 0; jj < 3; ++jj)
                d += dot4(aj[lane + 64 * jj], qw4[lane + 64 * jj]);
            d = wave_reduce_sum(d);
            if (lane == 0) {
                float g = d * invn[j] - ((i == j) ? 1.f : 0.f);
                acc += g * g;
            }
        }
        if (lane == 0) red[wave] = acc;
        __syncthreads();
        if (tid == 0) {
            float s = 0.f;
#pragma unroll
            for (int w = 0; w < 8; ++w) s += red[w];
            Gpart[i] = s;
        }
        return;
    }

    int b = bid;
    const int N4 = B * E / 4;
    // stage qW[b] = sum of 8 k-partials + b_att
    if (tid < E4) {
        const float4* p = (const float4*)part;
        size_t base = (size_t)b * E4 + tid;
        float4 r = ((const float4*)b_att)[tid];
#pragma unroll
        for (int i = 0; i < 8; ++i) {
            float4 s = p[base + (size_t)i * N4];
            r.x += s.x; r.y += s.y; r.z += s.z; r.w += s.w;
        }
        qw4[tid] = r;
    }
    __syncthreads();

    // per-lane qW fragment in registers
    float4 q0 = qw4[lane], q1 = qw4[lane + 64], q2 = qw4[lane + 128];

    // two independent online-softmax chains (ILP over the serial update dependency)
    float m0 = -3.4e38f, l0 = 0.f, m1 = -3.4e38f, l1 = 0.f;
    float4 p00 = make_float4(0.f,0.f,0.f,0.f), p01 = p00, p02 = p00;   // chain 0
    float4 p10 = p00, p11 = p00, p12 = p00;                            // chain 1

    const uint2*  xhb = (const uint2*)(xh + (size_t)b * S * E);
    const float4* xb  = (const float4*)(x + (size_t)b * S * E);
    int s0 = wave * 16;

#pragma unroll
    for (int i = 0; i < 16; i += 4) {
        float4 xA0, xA1, xA2, xB0, xB1, xB2, xC0, xC1, xC2, xD0, xD1, xD2;
        if (USE16) {
            const uint2* rA = xhb + (size_t)(s0 + i) * E4;
            const uint2* rB = rA + E4;
            const uint2* rC = rB + E4;
            const uint2* rD = rC + E4;
            xA0 = h4_to_f4(rA[lane]); xA1 = h4_to_f4(rA[lane + 64]); xA2 = h4_to_f4(rA[lane + 128]);
            xB0 = h4_to_f4(rB[lane]); xB1 = h4_to_f4(rB[lane + 64]); xB2 = h4_to_f4(rB[lane + 128]);
            xC0 = h4_to_f4(rC[lane]); xC1 = h4_to_f4(rC[lane + 64]); xC2 = h4_to_f4(rC[lane + 128]);
            xD0 = h4_to_f4(rD[lane]); xD1 = h4_to_f4(rD[lane + 64]); xD2 = h4_to_f4(rD[lane + 128]);
        } else {
            const float4* rA = xb + (size_t)(s0 + i) * E4;
            const float4* rB = rA + E4;
            const float4* rC = rB + E4;
            const float4* rD = rC + E4;
            xA0 = rA[lane]; xA1 = rA[lane + 64]; xA2 = rA[lane + 128];
            xB0 = rB[lane]; xB1 = rB[lane + 64]; xB2 = rB[lane + 128];
            xC0 = rC[lane]; xC1 = rC[lane + 64]; xC2 = rC[lane + 128];
            xD0 = rD[lane]; xD1 = rD[lane + 64]; xD2 = rD[lane + 128];
        }
        float dA = dot4(xA0, q0) + dot4(xA1, q1) + dot4(xA2, q2);
        float dB = dot4(xB0, q0) + dot4(xB1, q1) + dot4(xB2, q2);
        float dC = dot4(xC0, q0) + dot4(xC1, q1) + dot4(xC2, q2);
        float dD = dot4(xD0, q0) + dot4(xD1, q1) + dot4(xD2, q2);
#pragma unroll
        for (int off = 32; off; off >>= 1) {
            dA += __shfl_xor(dA, off);
            dB += __shfl_xor(dB, off);
            dC += __shfl_xor(dC, off);
            dD += __shfl_xor(dD, off);
        }
        // chain 0 update (rows A,B)
        float tm0 = fmaxf(m0, fmaxf(dA, dB));
        float sc0 = __expf(m0 - tm0);
        float eA = __expf(dA - tm0), eB = __expf(dB - tm0);
        // chain 1 update (rows C,D) — independent of chain 0
        float tm1 = fmaxf(m1, fmaxf(dC, dD));
        float sc1 = __expf(m1 - tm1);
        float eC = __expf(dC - tm1), eD = __expf(dD - tm1);

        l0 = l0 * sc0 + eA + eB;
        l1 = l1 * sc1 + eC + eD;
        p00.x = p00.x * sc0 + eA * xA0.x + eB * xB0.x;
        p00.y = p00.y * sc0 + eA * xA0.y + eB * xB0.y;
        p00.z = p00.z * sc0 + eA * xA0.z + eB * xB0.z;
        p00.w = p00.w * sc0 + eA * xA0.w + eB * xB0.w;
        p10.x = p10.x * sc1 + eC * xC0.x + eD * xD0.x;
        p10.y = p10.y * sc1 + eC * xC0.y + eD * xD0.y;
        p10.z = p10.z * sc1 + eC * xC0.z + eD * xD0.z;
        p10.w = p10.w * sc1 + eC * xC0.w + eD * xD0.w;
        p01.x = p01.x * sc0 + eA * xA1.x + eB * xB1.x;
        p01.y = p01.y * sc0 + eA * xA1.y + eB * xB1.y;
        p01.z = p01.z * sc0 + eA * xA1.z + eB * xB1.z;
        p01.w = p01.w * sc0 + eA * xA1.w + eB * xB1.w;
        p11.x = p11.x * sc1 + eC * xC1.x + eD * xD1.x;
        p11.y = p11.y * sc1 + eC * xC1.y + eD * xD1.y;
        p11.z = p11.z * sc1 + eC * xC1.z + eD * xD1.z;
        p11.w = p11.w * sc1 + eC * xC1.w + eD * xD1.w;
        p02.x = p02.x * sc0 + eA * xA2.x + eB * xB2.x;
        p02.y = p02.y * sc0 + eA * xA2.y + eB * xB2.y;
        p02.z = p02.z * sc0 + eA * xA2.z + eB * xB2.z;
        p02.w = p02.w * sc0 + eA * xA2.w + eB * xB2.w;
        p12.x = p12.x * sc1 + eC * xC2.x + eD * xD2.x;
        p12.y = p12.y * sc1 + eC * xC2.y + eD * xD2.y;
        p12.z = p12.z * sc1 + eC * xC2.z + eD * xD2.z;
        p12.w = p12.w * sc1 + eC * xC2.w + eD * xD2.w;
        m0 = tm0;
        m1 = tm1;
    }

    // merge the two chains (exact rescale)
    float m = fmaxf(m0, m1);
    float f0 = __expf(m0 - m), f1 = __expf(m1 - m);
    float l = l0 * f0 + l1 * f1;
    float4 a0, a1, a2;
    a0.x = p00.x * f0 + p10.x * f1; a0.y = p00.y * f0 + p10.y * f1;
    a0.z = p00.z * f0 + p10.z * f1; a0.w = p00.w * f0 + p10.w * f1;
    a1.x = p01.x * f0 + p11.x * f1; a1.y = p01.y * f0 + p11.y * f1;
    a1.z = p01.z * f0 + p11.z * f1; a1.w = p01.w * f0 + p11.w * f1;
    a2.x = p02.x * f0 + p12.x * f1; a2.y = p02.y * f0 + p12.y * f1;
    a2.z = p02.z * f0 + p12.z * f1; a2.w = p02.w * f0 + p12.w * f1;

    // per-wave partials to LDS
    zw[wave][lane] = a0;
    zw[wave][lane + 64] = a1;
    zw[wave][lane + 128] = a2;
    if (lane == 0) { wm[wave] = m; wl[wave] = l; }
    __syncthreads();

    // combine 8 waves with rescale (threads 0..191)
    if (tid < E4) {
        float M = wm[0];
#pragma unroll
        for (int w = 1; w < 8; ++w) M = fmaxf(M, wm[w]);
        float L = 0.f;
        float4 z = make_float4(0.f, 0.f, 0.f, 0.f);
#pragma unroll
        for (int w = 0; w < 8; ++w) {
            float f = __expf(wm[w] - M);
            float4 a = zw[w][tid];
            z.x += f * a.x; z.y += f * a.y; z.z += f * a.z; z.w += f * a.w;
            L += f * wl[w];
        }
        float invL = 1.0f / L;
        z.x *= invL; z.y *= invL; z.z *= invL; z.w *= invL;
        ((float4*)z_s)[(size_t)b * E4 + tid] = z;
    }
}

// ---------------- K4: composition + reconstruction + margin (768 thr) ----------------
__global__ __launch_bounds__(768) void recon_margin_kernel(const float* __restrict__ z_s,
                                                           const float* __restrict__ WredT,
                                                           const float* __restrict__ b_red,
                                                           const float* __restrict__ aspect_W,
                                                           const int* __restrict__ neg_idx,
                                                           float* __restrict__ recon,
                                                           float* __restrict__ mpart) {
    int b = blockIdx.x;
    int tid = threadIdx.x, wave = tid >> 6, lane = tid & 63;
    __shared__ __align__(16) float4 z4[E4];
    __shared__ float comp[NA];
    __shared__ __align__(16) float r_sh[E];
    __shared__ float red[12];
    __shared__ float dots[12];

    if (tid < E4) z4[tid] = ((const float4*)(z_s + (size_t)b * E))[tid];
    __syncthreads();

    for (int a = wave; a < NA; a += 12) {
        const float4* wr = (const float4*)(WredT + (size_t)a * E);
        float d = 0.f;
#pragma unroll
        for (int j = 0; j < 3; ++j)
            d += dot4(wr[lane + 64 * j], z4[lane + 64 * j]);
        d = wave_reduce_sum(d);
        if (lane == 0) comp[a] = d + b_red[a];
    }
    __syncthreads();

    if (wave == 0) {
        float v = (lane < NA) ? comp[lane] : -3.4e38f;
        float m = wave_reduce_max(v);
        m = __shfl(m, 0);
        float e = (lane < NA) ? expf(v - m) : 0.f;
        float ssum = wave_reduce_sum(e);
        ssum = __shfl(ssum, 0);
        if (lane < NA) comp[lane] = e / ssum;
    }
    __syncthreads();

    float r = 0.f;
    for (int a = 0; a < NA; ++a)
        r += comp[a] * aspect_W[(size_t)a * E + tid];
    recon[(size_t)b * E + tid] = r;
    r_sh[tid] = r;
    float sq = wave_reduce_sum(r * r);
    if (lane == 0) red[wave] = sq;
    __syncthreads();
    float tot = 0.f;
#pragma unroll
    for (int w = 0; w < 12; ++w) tot += red[w];
    float inv = 1.0f / fmaxf(sqrtf(tot), 1e-12f);

    if (wave <= NNEG) {
        int row = (wave == 0) ? b : neg_idx[b * NNEG + (wave - 1)];
        const float4* zr = (const float4*)(z_s + (size_t)row * E);
        const float4* rr = (const float4*)r_sh;
        float acc = 0.f;
#pragma unroll
        for (int j = 0; j < 3; ++j)
            acc += dot4(zr[lane + 64 * j], rr[lane + 64 * j]);
        acc = wave_reduce_sum(acc);
        if (lane == 0) dots[wave] = acc;
    }
    __syncthreads();
    if (tid == 0) {
        float pos = dots[0] * inv;
        float ssum = 0.f;
        for (int n = 1; n <= NNEG; ++n)
            ssum += fmaxf(1.f - pos + dots[n] * inv, 0.f);
        mpart[b] = ssum;
    }
}

// ---------------- K5: final scalar loss ----------------
__global__ __launch_bounds__(256) void loss_kernel(const float* __restrict__ Gpart,
                                                   const float* __restrict__ mpart,
                                                   float* __restrict__ loss_out) {
    int tid = threadIdx.x, wave = tid >> 6, lane = tid & 63;
    __shared__ float ra[4], rb[4];
    float fr = (tid < NA) ? Gpart[tid] : 0.f;
    fr = wave_reduce_sum(fr);
    if (lane == 0) ra[wave] = fr;
    float mp = mpart[tid];
    mp = wave_reduce_sum(mp);
    if (lane == 0) rb[wave] = mp;
    __syncthreads();
    if (tid == 0) {
        float frob = sqrtf(ra[0] + ra[1] + ra[2] + ra[3]);
        float msum = rb[0] + rb[1] + rb[2] + rb[3];
        loss_out[0] = frob + msum * (1.0f / (float)(B * NNEG));
    }
}

extern "C" void kernel_launch(void* const* d_in, const int* in_sizes, int n_in,
                              void* d_out, int out_size, void* d_ws, size_t ws_size,
                              hipStream_t stream) {
    const float* x        = (const float*)d_in[0];
    const float* W_att    = (const float*)d_in[1];
    const float* b_att    = (const float*)d_in[2];
    const float* W_red    = (const float*)d_in[3];
    const float* b_red    = (const float*)d_in[4];
    const float* aspect_W = (const float*)d_in[5];
    const int*   neg_idx  = (const int*)d_in[6];

    float* out   = (float*)d_out;
    float* z_s   = out;                       // [B,E]
    float* recon = out + (size_t)B * E;       // [B,E]
    float* loss  = out + (size_t)2 * B * E;   // [1]

    float* ws    = (float*)d_ws;
    float* q     = ws;                        // 2*B*E
    float* part2 = q + (size_t)2 * B * E;     // 8*B*E
    float* WredT = part2 + (size_t)8 * B * E; // NA*E
    float* invn  = WredT + (size_t)NA * E;    // 32
    float* Gpart = invn + 32;                 // 32
    float* mpart = Gpart + 32;                // B
    float* endf  = mpart + B;

    size_t base_floats = (size_t)(endf - ws);
    size_t need = base_floats * sizeof(float) + (size_t)B * S * E * sizeof(__half);
    bool use16 = (ws_size >= need);
    __half* xh = (__half*)(ws + base_floats);

    if (use16) {
        mean_prep_kernel<1><<<2 * B + NA, 768, 0, stream>>>(x, W_red, aspect_W, q, WredT, invn, xh);
        qw_partial_kernel<<<dim3(4, 12, 8), 256, 0, stream>>>(q, W_att, part2);
        attn_ortho_kernel<1><<<B + NA, 512, 0, stream>>>(x, xh, part2, b_att, aspect_W, invn, z_s, Gpart);
    } else {
        mean_prep_kernel<0><<<2 * B + NA, 768, 0, stream>>>(x, W_red, aspect_W, q, WredT, invn, xh);
        qw_partial_kernel<<<dim3(4, 12, 8), 256, 0, stream>>>(q, W_att, part2);
        attn_ortho_kernel<0><<<B + NA, 512, 0, stream>>>(x, xh, part2, b_att, aspect_W, invn, z_s, Gpart);
    }
    recon_margin_kernel<<<B, 768, 0, stream>>>(z_s, WredT, b_red, aspect_W, neg_idx, recon, mpart);
    loss_kernel<<<1, 256, 0, stream>>>(Gpart, mpart, loss);
}